// Round 1
// 930.935 us; speedup vs baseline: 2.0187x; 2.0187x over previous
//
#include <hip/hip_runtime.h>
#include <hip/hip_bf16.h>

// Problem constants
#define B_ 4
#define S_ 2048
#define E_ 2048
#define H_ 16
#define D_ 128
#define M_ (B_*S_)   // 8192 rows

typedef __attribute__((ext_vector_type(8))) short short8;
typedef __attribute__((ext_vector_type(4))) float f32x4;

__device__ __forceinline__ unsigned short f2bf(float f) {
  union { __hip_bfloat16 h; unsigned short u; } c;
  c.h = __float2bfloat16(f);
  return c.u;
}

__device__ __forceinline__ void gld_lds16(const void* g, void* l) {
  __builtin_amdgcn_global_load_lds((const __attribute__((address_space(1))) void*)g,
                                   (__attribute__((address_space(3))) void*)l, 16, 0, 0);
}

// ---------------- fp32 -> bf16 cast (vectorized) ----------------
__global__ __launch_bounds__(256) void cast_bf16_kernel(const float* __restrict__ in,
                                                        unsigned short* __restrict__ out,
                                                        int n4) {
  int i = blockIdx.x * 256 + threadIdx.x;
  if (i >= n4) return;
  float4 v = ((const float4*)in)[i];
  ushort4 o;
  o.x = f2bf(v.x); o.y = f2bf(v.y); o.z = f2bf(v.z); o.w = f2bf(v.w);
  ((ushort4*)out)[i] = o;
}

// ---------------- GEMM: C[M,N] = A[M,K] @ W[N,K]^T + bias ----------------
// m97 structure: 128x128 tile, BK=32, 4 waves (2x2 of 64x64), global_load_lds w16.
template <typename OutT>
__global__ __launch_bounds__(256) void gemm_bt(const unsigned short* __restrict__ A,
                                               const unsigned short* __restrict__ W,
                                               const float* __restrict__ bias,
                                               OutT* __restrict__ C,
                                               int M, int N, int K) {
  __shared__ unsigned short As[128 * 32];
  __shared__ unsigned short Bs[128 * 32];
  const int tid  = threadIdx.x;
  const int lane = tid & 63;
  const int wid  = tid >> 6;
  const int m0 = blockIdx.y * 128;
  const int n0 = blockIdx.x * 128;
  const int wr = (wid >> 1) * 64;   // wave row offset in tile
  const int wc = (wid & 1) * 64;    // wave col offset in tile
  const int lr  = lane & 15;
  const int lk8 = (lane >> 4) * 8;

  f32x4 acc[4][4];
#pragma unroll
  for (int i = 0; i < 4; i++)
#pragma unroll
    for (int j = 0; j < 4; j++) acc[i][j] = (f32x4){0.f, 0.f, 0.f, 0.f};

  // staging: tile is 128 rows x 32 cols bf16 = 8192 B; 256 thr x 16 B = 4096 B/pass
  const int o0 = tid * 16;            // byte offset in tile, pass 0
  const int row0 = o0 >> 6, colb0 = o0 & 63;
  const int o1 = o0 + 4096;           // pass 1
  const int row1 = o1 >> 6, colb1 = o1 & 63;
  const int ldsb0 = wid * 1024;       // wave-uniform LDS byte base, pass 0
  const int ldsb1 = wid * 1024 + 4096;

  for (int kt = 0; kt < K; kt += 32) {
    gld_lds16(A + (size_t)(m0 + row0) * K + kt + (colb0 >> 1), (char*)As + ldsb0);
    gld_lds16(A + (size_t)(m0 + row1) * K + kt + (colb1 >> 1), (char*)As + ldsb1);
    gld_lds16(W + (size_t)(n0 + row0) * K + kt + (colb0 >> 1), (char*)Bs + ldsb0);
    gld_lds16(W + (size_t)(n0 + row1) * K + kt + (colb1 >> 1), (char*)Bs + ldsb1);
    __syncthreads();

    short8 af[4], bf[4];
#pragma unroll
    for (int i = 0; i < 4; i++) af[i] = *(const short8*)&As[(wr + i * 16 + lr) * 32 + lk8];
#pragma unroll
    for (int j = 0; j < 4; j++) bf[j] = *(const short8*)&Bs[(wc + j * 16 + lr) * 32 + lk8];
#pragma unroll
    for (int i = 0; i < 4; i++)
#pragma unroll
      for (int j = 0; j < 4; j++)
        acc[i][j] = __builtin_amdgcn_mfma_f32_16x16x32_bf16(af[i], bf[j], acc[i][j], 0, 0, 0);
    __syncthreads();
  }

  // epilogue: C/D layout col=lane&15, row=(lane>>4)*4+r  [m89-verified]
#pragma unroll
  for (int i = 0; i < 4; i++) {
    const int gm = m0 + wr + i * 16 + (lane >> 4) * 4;
#pragma unroll
    for (int j = 0; j < 4; j++) {
      const int gn = n0 + wc + j * 16 + lr;
      const float bv = bias[gn];
#pragma unroll
      for (int r = 0; r < 4; r++) {
        const float v = acc[i][j][r] + bv;
        if constexpr (sizeof(OutT) == 2)
          ((unsigned short*)C)[(size_t)(gm + r) * N + gn] = f2bf(v);
        else
          ((float*)C)[(size_t)(gm + r) * N + gn] = v;
      }
    }
  }
}

// ---------------- causal flash attention ----------------
// 4 waves (256 thr) per block; each wave owns 16 consecutive query rows
// (64-row q-tile per block). KV steps of 32, staged cooperatively in LDS:
//   Ks[32][128] bf16, XOR-swizzled (cb ^= (row&7)<<4) via pre-swizzled
//     global_load_lds source (linear LDS dest, rule 21)
//   Vt[128][32] bf16, transposed, chunk-swizzled:
//     idx(d,kv) = d*32 + (((kv>>3) ^ ((d>>1)&3) ^ ((d>>4)&3))<<3) + (kv&7)
//     (d>>1 term spreads read lanes (d=d0*16+lr); d>>4 term spreads write
//      lanes (d=c16+j, c16 lane-varying) -> writes ~2-4-way vs old 16-way)
// MFMA layouts (16x16x32 bf16) identical to the verified single-wave kernel.
__global__ __launch_bounds__(256) void flash_attn(const unsigned short* __restrict__ Q,
                                                  const unsigned short* __restrict__ K,
                                                  const unsigned short* __restrict__ V,
                                                  unsigned short* __restrict__ Ctx) {
  __shared__ unsigned short Ks[32 * 128];   // 8 KB, swizzled K tile
  __shared__ unsigned short Vt[128 * 32];   // 8 KB, swizzled V^T tile
  __shared__ unsigned short Pl[4 * 16 * 32]; // 4 KB, per-wave P tiles

  const int tid  = threadIdx.x;
  const int lane = tid & 63;
  const int wid  = tid >> 6;
  const int lr  = lane & 15;
  const int lg  = lane >> 4;
  const int lk8 = lg * 8;
  const int qblk = blockIdx.x * 64;         // block q-tile base
  const int q0w  = qblk + wid * 16;         // this wave's q rows
  const int h  = blockIdx.y;
  const int b  = blockIdx.z;
  const size_t base = ((size_t)b * S_) * E_ + (size_t)h * D_;
  const unsigned short* __restrict__ Kh = K + base;
  const unsigned short* __restrict__ Vh = V + base;
  unsigned short* Plw = Pl + wid * 512;

  // K staging geometry: tile 32 rows x 256 B; 256 thr x 16 B = 4096 B/pass, 2 passes.
  // LDS dest is linear (wave-uniform base + lane*16); global source col is
  // XOR-swizzled so that LDS holds logical (row, cb ^ ((row&7)<<4)).
  const int oK0 = tid * 16;
  const int rK0 = oK0 >> 8;                 // rows 0..15
  const int cK0 = (oK0 & 255) ^ ((rK0 & 7) << 4);
  const int rK1 = (oK0 + 4096) >> 8;        // rows 16..31
  const int cK1 = (oK0 & 255) ^ ((rK1 & 7) << 4);
  const int ldsK0 = wid * 1024;             // wave-uniform base, pass 0
  const int ldsK1 = 4096 + wid * 1024;      // pass 1

  // V staging geometry: thread loads 16 u16 of one kv row
  const int vr  = tid >> 3;                 // kv row 0..31
  const int c16 = (tid & 7) * 16;           // d base 0..112

  // Q fragments: rows q0w+lr, feature k = kk*32 + lk8 .. +8
  short8 qf[4];
#pragma unroll
  for (int kk = 0; kk < 4; kk++)
    qf[kk] = *(const short8*)&Q[base + (size_t)(q0w + lr) * E_ + kk * 32 + lk8];

  f32x4 o[8];
#pragma unroll
  for (int d0 = 0; d0 < 8; d0++) o[d0] = (f32x4){0.f, 0.f, 0.f, 0.f};
  float mrow[4] = {-INFINITY, -INFINITY, -INFINITY, -INFINITY};
  float lsum[4] = {0.f, 0.f, 0.f, 0.f};
  const float scale = 0.08838834764831845f;  // 1/sqrt(128)

  for (int kv0 = 0; kv0 < qblk + 64; kv0 += 32) {
    const bool active = (kv0 < q0w + 16);   // wave still has unmasked kv cols

    // ---- cooperative staging (all 256 threads) ----
    gld_lds16(Kh + (size_t)(kv0 + rK0) * E_ + (cK0 >> 1), (char*)Ks + ldsK0);
    gld_lds16(Kh + (size_t)(kv0 + rK1) * E_ + (cK1 >> 1), (char*)Ks + ldsK1);
    {
      short8 vv0 = *(const short8*)&Vh[(size_t)(kv0 + vr) * E_ + c16];
      short8 vv1 = *(const short8*)&Vh[(size_t)(kv0 + vr) * E_ + c16 + 8];
#pragma unroll
      for (int j = 0; j < 8; j++) {
        const int d = c16 + j;
        const int sw = ((d >> 1) & 3) ^ ((d >> 4) & 3);
        Vt[d * 32 + ((((vr >> 3) ^ sw)) << 3) + (vr & 7)] = ((const unsigned short*)&vv0)[j];
      }
#pragma unroll
      for (int j = 0; j < 8; j++) {
        const int d = c16 + 8 + j;
        const int sw = ((d >> 1) & 3) ^ ((d >> 4) & 3);
        Vt[d * 32 + ((((vr >> 3) ^ sw)) << 3) + (vr & 7)] = ((const unsigned short*)&vv1)[j];
      }
    }
    __syncthreads();   // staging complete (drains vmcnt for gld_lds too)

    if (active) {
      // S = Q K^T for two 16-col chunks (K from swizzled LDS)
      f32x4 s0 = (f32x4){0.f, 0.f, 0.f, 0.f};
      f32x4 s1 = (f32x4){0.f, 0.f, 0.f, 0.f};
      const int swK = (lr & 7) << 4;
#pragma unroll
      for (int kk = 0; kk < 4; kk++) {
        const int cb = (kk * 64 + lg * 16) ^ swK;
        short8 k0 = *(const short8*)((const char*)Ks + lr * 256 + cb);
        short8 k1 = *(const short8*)((const char*)Ks + (16 + lr) * 256 + cb);
        s0 = __builtin_amdgcn_mfma_f32_16x16x32_bf16(qf[kk], k0, s0, 0, 0, 0);
        s1 = __builtin_amdgcn_mfma_f32_16x16x32_bf16(qf[kk], k1, s1, 0, 0, 0);
      }

      // online softmax (per row r; rows replicated across the 16 lanes of each group)
      float alpha[4], p0[4], p1[4];
#pragma unroll
      for (int r = 0; r < 4; r++) {
        const int qrow = q0w + lg * 4 + r;
        float v0 = (kv0 + lr <= qrow) ? s0[r] * scale : -INFINITY;
        float v1 = (kv0 + 16 + lr <= qrow) ? s1[r] * scale : -INFINITY;
        float pm = fmaxf(v0, v1);
#pragma unroll
        for (int off = 1; off < 16; off <<= 1) pm = fmaxf(pm, __shfl_xor(pm, off));
        const float mnew = fmaxf(mrow[r], pm);
        alpha[r] = __expf(mrow[r] - mnew);   // first iter: exp(-inf)=0
        p0[r] = __expf(v0 - mnew);
        p1[r] = __expf(v1 - mnew);
        mrow[r] = mnew;
        float ps = p0[r] + p1[r];
#pragma unroll
        for (int off = 1; off < 16; off <<= 1) ps += __shfl_xor(ps, off);
        lsum[r] = lsum[r] * alpha[r] + ps;
      }

      // rescale O
#pragma unroll
      for (int d0 = 0; d0 < 8; ++d0) {
        f32x4 t = o[d0];
        t[0] *= alpha[0]; t[1] *= alpha[1]; t[2] *= alpha[2]; t[3] *= alpha[3];
        o[d0] = t;
      }

      // P (C-layout) -> per-wave LDS tile in A-operand feed layout
#pragma unroll
      for (int r = 0; r < 4; r++) {
        Plw[(lg * 4 + r) * 32 + lr]      = f2bf(p0[r]);
        Plw[(lg * 4 + r) * 32 + 16 + lr] = f2bf(p1[r]);
      }
    }
    __syncthreads();   // Pl visible within wave-group

    if (active) {
      const short8 pa = *(const short8*)&Plw[lr * 32 + lk8];
#pragma unroll
      for (int d0 = 0; d0 < 8; ++d0) {
        const int d = d0 * 16 + lr;
        const int sw = ((d >> 1) & 3) ^ ((d >> 4) & 3);
        const short8 vb = *(const short8*)&Vt[d * 32 + ((lg ^ sw) << 3)];
        o[d0] = __builtin_amdgcn_mfma_f32_16x16x32_bf16(pa, vb, o[d0], 0, 0, 0);
      }
    }
    __syncthreads();   // protect Ks/Vt/Pl before next staging pass
  }

  // normalize + store ctx (bf16), layout [B,S,H*D]
#pragma unroll
  for (int d0 = 0; d0 < 8; ++d0) {
#pragma unroll
    for (int r = 0; r < 4; r++) {
      const float val = o[d0][r] / lsum[r];
      Ctx[base + (size_t)(q0w + lg * 4 + r) * E_ + d0 * 16 + lr] = f2bf(val);
    }
  }
}

// ---------------- launcher ----------------
extern "C" void kernel_launch(void* const* d_in, const int* in_sizes, int n_in,
                              void* d_out, int out_size, void* d_ws, size_t ws_size,
                              hipStream_t stream) {
  const float* x  = (const float*)d_in[0];
  // d_in[1] = causal_mask (tril) — implemented analytically
  const float* wq = (const float*)d_in[2];
  const float* bq = (const float*)d_in[3];
  const float* wk = (const float*)d_in[4];
  const float* bk = (const float*)d_in[5];
  const float* wv = (const float*)d_in[6];
  const float* bv = (const float*)d_in[7];
  const float* wo = (const float*)d_in[8];
  const float* bo = (const float*)d_in[9];
  float* out = (float*)d_out;

  char* ws = (char*)d_ws;
  const size_t MB = 1024 * 1024;
  unsigned short* xb  = (unsigned short*)(ws);             // 32 MB
  unsigned short* wqb = (unsigned short*)(ws + 32 * MB);   // 8 MB
  unsigned short* wkb = (unsigned short*)(ws + 40 * MB);   // 8 MB
  unsigned short* wvb = (unsigned short*)(ws + 48 * MB);   // 8 MB
  unsigned short* wob = (unsigned short*)(ws + 56 * MB);   // 8 MB
  unsigned short* Qb  = (unsigned short*)(ws + 64 * MB);   // 32 MB
  unsigned short* Kb  = (unsigned short*)(ws + 96 * MB);   // 32 MB
  unsigned short* Vb  = (unsigned short*)(ws + 128 * MB);  // 32 MB
  unsigned short* Cb  = (unsigned short*)(ws + 160 * MB);  // 32 MB -> 192 MB total

  const int nx4 = M_ * E_ / 4;   // x elements /4
  const int nw4 = E_ * E_ / 4;   // weight elements /4
  cast_bf16_kernel<<<nx4 / 256, 256, 0, stream>>>(x,  xb,  nx4);
  cast_bf16_kernel<<<nw4 / 256, 256, 0, stream>>>(wq, wqb, nw4);
  cast_bf16_kernel<<<nw4 / 256, 256, 0, stream>>>(wk, wkb, nw4);
  cast_bf16_kernel<<<nw4 / 256, 256, 0, stream>>>(wv, wvb, nw4);
  cast_bf16_kernel<<<nw4 / 256, 256, 0, stream>>>(wo, wob, nw4);

  dim3 gg(E_ / 128, M_ / 128);   // (16, 64)
  gemm_bt<unsigned short><<<gg, 256, 0, stream>>>(xb, wqb, bq, Qb, M_, E_, E_);
  gemm_bt<unsigned short><<<gg, 256, 0, stream>>>(xb, wkb, bk, Kb, M_, E_, E_);
  gemm_bt<unsigned short><<<gg, 256, 0, stream>>>(xb, wvb, bv, Vb, M_, E_, E_);

  flash_attn<<<dim3(S_ / 64, H_, B_), 256, 0, stream>>>(Qb, Kb, Vb, Cb);

  gemm_bt<float><<<gg, 256, 0, stream>>>(Cb, wob, bo, out, M_, E_, E_);
}